// Round 3
// baseline (21263.004 us; speedup 1.0000x reference)
//
#include <hip/hip_runtime.h>

// TrajectoryDecoder r3: weights-stationary GRU. MFMA 32x32x16 bf16.
// BK=49152, T=30, H=256. Block = 96 seqs, 512 thr (8 waves), grid 512
// (= exactly 2 blocks/CU resident; LDS 63.7 KB keeps both).
// Each wave preloads its 48 weight B-fragments (3 gates x 16 ks, 192 VGPRs)
// ONCE; the 30-step t-loop does only ds_read_b128 (A=h) + MFMA-from-regs.
// h carried in fp32 regs; bf16 copy in LDS for next step's A-operand.

typedef __attribute__((ext_vector_type(8))) short short8;
typedef __bf16 bf16x8 __attribute__((ext_vector_type(8)));
typedef float f32x16 __attribute__((ext_vector_type(16)));
typedef float f32x4 __attribute__((ext_vector_type(4)));

#define HSTR 264               // Hb stride (bf16): 528B rows; measured ~0 conflicts (r2)
#define NSEQ_BLK 96
#define WHH3_ELEMS (24 * 16 * 64 * 8)  // 196608 = 768x256
#define WH0_ELEMS (8 * 20 * 64 * 8)    // 81920

static __device__ __forceinline__ unsigned short f2bf(float f) {
  unsigned u = __builtin_bit_cast(unsigned, f);
  u += 0x7fffu + ((u >> 16) & 1u);   // RNE
  return (unsigned short)(u >> 16);
}
static __device__ __forceinline__ bf16x8 ldfrag(const unsigned short* p) {
  return __builtin_bit_cast(bf16x8, *(const short8*)p);
}
static __device__ __forceinline__ float fsig(float x) {
  return __builtin_amdgcn_rcpf(1.f + __builtin_amdgcn_exp2f(-1.44269504f * x));
}
static __device__ __forceinline__ float ftanh(float x) {
  return 1.f - 2.f * __builtin_amdgcn_rcpf(1.f + __builtin_amdgcn_exp2f(2.88539008f * x));
}
static __device__ __forceinline__ float dpp16sum(float x) {
  x += __builtin_bit_cast(float, __builtin_amdgcn_update_dpp(0, __builtin_bit_cast(int, x), 0xB1, 0xF, 0xF, true));
  x += __builtin_bit_cast(float, __builtin_amdgcn_update_dpp(0, __builtin_bit_cast(int, x), 0x4E, 0xF, 0xF, true));
  x += __builtin_bit_cast(float, __builtin_amdgcn_update_dpp(0, __builtin_bit_cast(int, x), 0x141, 0xF, 0xF, true));
  x += __builtin_bit_cast(float, __builtin_amdgcn_update_dpp(0, __builtin_bit_cast(int, x), 0x140, 0xF, 0xF, true));
  return x;
}

// ---- prep: pack W_hh slice-major: [(g*8+w)*16 + ks][lane][8] ----
// row(N) = g*256 + w*32 + (lane&31), k = ks*16 + (lane>>5)*8 + j
__global__ void prep_whh3_k(const float* __restrict__ Whh, unsigned short* __restrict__ Whhp3) {
  int i = blockIdx.x * 256 + threadIdx.x;
  if (i >= WHH3_ELEMS) return;
  int j = i & 7;
  int lane = (i >> 3) & 63;
  int rest = i >> 9;            // (g*8+w)*16 + ks
  int ks = rest & 15;
  int sw = rest >> 4;           // 0..23
  int g = sw >> 3, w = sw & 7;
  int row = g * 256 + w * 32 + (lane & 31);
  int k = ks * 16 + ((lane >> 5) << 3) + j;
  Whhp3[i] = f2bf(Whh[row * 256 + k]);
}

// ---- prep: pack W_h0 (256 x 290, K padded to 320): [nt][ks 0..19][lane][8] ----
__global__ void prep_wh0_k(const float* __restrict__ Wh0, unsigned short* __restrict__ Wh0p) {
  int i = blockIdx.x * 256 + threadIdx.x;
  if (i >= WH0_ELEMS) return;
  int j = i & 7;
  int lane = (i >> 3) & 63;
  int rest = i >> 9;            // nt*20 + ks
  int ks = rest % 20;
  int nt = rest / 20;
  int row = nt * 32 + (lane & 31);
  int k = ks * 16 + ((lane >> 5) << 3) + j;
  float v = (k < 290) ? Wh0[row * 290 + k] : 0.f;
  Wh0p[i] = f2bf(v);
}

// ---- prep: per-h-unit params [br,bz,bin,bhn, wr0,wr1, wz0,wz1, wn0,wn1, wo0,wo1] ----
__global__ void prep_gp_k(const float* __restrict__ bih, const float* __restrict__ bhh,
                          const float* __restrict__ Wih, const float* __restrict__ Wout,
                          float* __restrict__ gpo) {
  int n = threadIdx.x;   // 256
  gpo[n * 12 + 0]  = bih[n] + bhh[n];
  gpo[n * 12 + 1]  = bih[n + 256] + bhh[n + 256];
  gpo[n * 12 + 2]  = bih[n + 512];
  gpo[n * 12 + 3]  = bhh[n + 512];
  gpo[n * 12 + 4]  = Wih[n * 2 + 0];
  gpo[n * 12 + 5]  = Wih[n * 2 + 1];
  gpo[n * 12 + 6]  = Wih[(n + 256) * 2 + 0];
  gpo[n * 12 + 7]  = Wih[(n + 256) * 2 + 1];
  gpo[n * 12 + 8]  = Wih[(n + 512) * 2 + 0];
  gpo[n * 12 + 9]  = Wih[(n + 512) * 2 + 1];
  gpo[n * 12 + 10] = Wout[n];
  gpo[n * 12 + 11] = Wout[256 + n];
}

// ---------------- main fused GRU ----------------
__global__ __launch_bounds__(512, 4) void gru_main_k(
    const float* __restrict__ ctx, const float* __restrict__ goals,
    const float* __restrict__ emb, const float* __restrict__ bh0,
    const float* __restrict__ bout,
    const unsigned short* __restrict__ Wh0p,
    const unsigned short* __restrict__ Whhp3,
    const float* __restrict__ gp,
    float* __restrict__ out) {
  __shared__ __align__(16) unsigned short Hb[NSEQ_BLK * HSTR];   // 50688 B
  __shared__ __align__(16) float dpart[16 * NSEQ_BLK * 2];       // 12288 B
  __shared__ __align__(16) float posL[NSEQ_BLK * 2];             // 768 B
  // total 63744 B -> 2 blocks/CU

  const int tid = threadIdx.x;
  const int w = tid >> 6;
  const int l = tid & 63;
  const int l31 = l & 31;
  const int grp = l >> 5;
  const int seq0 = blockIdx.x * NSEQ_BLK;
  const int n0 = w * 32 + l31;

  // ---- preload this wave's 48 weight B-fragments into registers (held 30 steps)
  bf16x8 wR[16], wZ[16], wN[16];
#pragma unroll
  for (int ks = 0; ks < 16; ++ks) {
    wR[ks] = ldfrag(&Whhp3[(((0 * 8 + w) * 16 + ks) * 64 + l) * 8]);
    wZ[ks] = ldfrag(&Whhp3[(((1 * 8 + w) * 16 + ks) * 64 + l) * 8]);
    wN[ks] = ldfrag(&Whhp3[(((2 * 8 + w) * 16 + ks) * 64 + l) * 8]);
  }

  // ---------------- Phase 0: h0 = init_in @ W_h0^T + b_h0 ----------------
  f32x16 acc0[3];
  acc0[0] = f32x16{};
  acc0[1] = f32x16{};
  acc0[2] = f32x16{};
  unsigned short* As = Hb;   // overlay staging, stride 176
  for (int cc = 0; cc < 2; ++cc) {
    for (int i = tid; i < NSEQ_BLK * 160; i += 512) {
      int row = i / 160;
      int col = i - row * 160;
      int d = cc * 160 + col;
      int s = seq0 + row;
      int b = s / 6;
      float v;
      if (d < 256)      v = ctx[b * 256 + d];
      else if (d < 258) v = goals[s * 2 + (d - 256)];
      else if (d < 290) v = emb[b * 32 + (d - 258)];
      else              v = 0.f;
      As[row * 176 + col] = f2bf(v);
    }
    __syncthreads();
    for (int ks = 0; ks < 10; ++ks) {
      bf16x8 bf = ldfrag(&Wh0p[((w * 20 + cc * 10 + ks) * 64 + l) * 8]);
#pragma unroll
      for (int mc = 0; mc < 3; ++mc) {
        bf16x8 af = ldfrag(&As[(mc * 32 + l31) * 176 + ks * 16 + grp * 8]);
        acc0[mc] = __builtin_amdgcn_mfma_f32_32x32x16_bf16(af, bf, acc0[mc], 0, 0, 0);
      }
    }
    __syncthreads();
  }
  // epilogue: fp32 h in regs + bf16 copy in Hb
  float hreg[3][16];
  {
    float b0 = bh0[n0];
#pragma unroll
    for (int mc = 0; mc < 3; ++mc)
#pragma unroll
      for (int r = 0; r < 16; ++r) {
        int row = (r & 3) + 8 * (r >> 2) + 4 * grp;
        float h = acc0[mc][r] + b0;
        hreg[mc][r] = h;
        Hb[(mc * 32 + row) * HSTR + n0] = f2bf(h);
      }
  }
  if (tid < 192) posL[tid] = 0.f;

  float brr, bzz, bin_, bhn, wr0, wr1, wz0, wz1, wn0, wn1, wo0, wo1;
  {
    f32x4 g0 = *(const f32x4*)&gp[n0 * 12];
    f32x4 g1 = *(const f32x4*)&gp[n0 * 12 + 4];
    f32x4 g2 = *(const f32x4*)&gp[n0 * 12 + 8];
    brr = g0[0]; bzz = g0[1]; bin_ = g0[2]; bhn = g0[3];
    wr0 = g1[0]; wr1 = g1[1]; wz0 = g1[2]; wz1 = g1[3];
    wn0 = g2[0]; wn1 = g2[1]; wo0 = g2[2]; wo1 = g2[3];
  }
  const float bo0 = bout[0], bo1 = bout[1];
  __syncthreads();

  // ---------------- T recurrent steps ----------------
  for (int t = 0; t < 30; ++t) {
    f32x16 ar[3], az[3], an[3];
#pragma unroll
    for (int mc = 0; mc < 3; ++mc) { ar[mc] = f32x16{}; az[mc] = f32x16{}; an[mc] = f32x16{}; }

    // K-loop: pure LDS A-reads + MFMA from register-resident weights
#pragma unroll
    for (int ks = 0; ks < 16; ++ks) {
      const unsigned short* ab = &Hb[l31 * HSTR + ks * 16 + grp * 8];
#pragma unroll
      for (int mc = 0; mc < 3; ++mc) {
        bf16x8 af = ldfrag(ab + mc * 32 * HSTR);
        ar[mc] = __builtin_amdgcn_mfma_f32_32x32x16_bf16(af, wR[ks], ar[mc], 0, 0, 0);
        az[mc] = __builtin_amdgcn_mfma_f32_32x32x16_bf16(af, wZ[ks], az[mc], 0, 0, 0);
        an[mc] = __builtin_amdgcn_mfma_f32_32x32x16_bf16(af, wN[ks], an[mc], 0, 0, 0);
      }
    }
    __syncthreads();   // barrier1: all Hb reads done; posL(t-1) final everywhere

    // Phase B: gates + h update + delta partials (DPP 16-lane sums)
#pragma unroll
    for (int mc = 0; mc < 3; ++mc) {
#pragma unroll
      for (int q2 = 0; q2 < 4; ++q2) {
        int sb = mc * 32 + 8 * q2 + 4 * grp;
        f32x4 xyA = *(const f32x4*)&posL[sb * 2];
        f32x4 xyB = *(const f32x4*)&posL[sb * 2 + 4];
#pragma unroll
        for (int e = 0; e < 4; ++e) {
          int r = 4 * q2 + e;
          int s = sb + e;
          float x = (e == 0) ? xyA[0] : (e == 1) ? xyA[2] : (e == 2) ? xyB[0] : xyB[2];
          float y = (e == 0) ? xyA[1] : (e == 1) ? xyA[3] : (e == 2) ? xyB[1] : xyB[3];
          float h = hreg[mc][r];
          float rg = fsig(ar[mc][r] + brr + x * wr0 + y * wr1);
          float zg = fsig(az[mc][r] + bzz + x * wz0 + y * wz1);
          float ng = ftanh(fmaf(rg, an[mc][r] + bhn, fmaf(x, wn0, fmaf(y, wn1, bin_))));
          float hnew = fmaf(zg, h - ng, ng);     // (1-z)*n + z*h
          hreg[mc][r] = hnew;
          Hb[s * HSTR + n0] = f2bf(hnew);
          float dx = dpp16sum(hnew * wo0);
          float dy = dpp16sum(hnew * wo1);
          if ((l & 15) == 0) {
            int p16 = w * 2 + ((l >> 4) & 1);
            dpart[(p16 * NSEQ_BLK + s) * 2]     = dx;
            dpart[(p16 * NSEQ_BLK + s) * 2 + 1] = dy;
          }
        }
      }
    }
    __syncthreads();   // barrier2: Hb h-writes + dpart visible

    // Phase C (threads 0-191): pos update + raw pred store; overlaps next K-loop
    if (tid < 192) {
      int s = tid >> 1, c = tid & 1;
      float d = (c == 0) ? bo0 : bo1;
#pragma unroll
      for (int q = 0; q < 16; ++q) d += dpart[(q * NSEQ_BLK + s) * 2 + c];
      float p = posL[tid] + d;
      posL[tid] = p;
      out[((seq0 + s) * 30 + t) * 2 + c] = p;
    }
  }
}

// ---- correction: out = pred + (goal - pred_T) * (t+1)/30, in place ----
__global__ void corr_k(float* __restrict__ out, const float* __restrict__ goals) {
  __shared__ float buf[240];
  int tid = threadIdx.x;
  int s0 = blockIdx.x * 4;
  float v = 0.f;
  if (tid < 240) { v = out[s0 * 60 + tid]; buf[tid] = v; }
  __syncthreads();
  if (tid < 240) {
    int sl = tid / 60;
    int rem = tid - sl * 60;
    int t = rem >> 1, c = rem & 1;
    float pT = buf[sl * 60 + 58 + c];
    float g = goals[(s0 + sl) * 2 + c];
    out[s0 * 60 + tid] = v + (g - pT) * ((float)(t + 1) * (1.f / 30.f));
  }
}

extern "C" void kernel_launch(void* const* d_in, const int* in_sizes, int n_in,
                              void* d_out, int out_size, void* d_ws, size_t ws_size,
                              hipStream_t stream) {
  (void)in_sizes; (void)n_in; (void)out_size; (void)ws_size;
  const float* ctx  = (const float*)d_in[0];
  const float* goals= (const float*)d_in[1];
  const float* emb  = (const float*)d_in[2];
  const float* Wh0  = (const float*)d_in[3];
  const float* bh0  = (const float*)d_in[4];
  const float* Wih  = (const float*)d_in[5];
  const float* Whh  = (const float*)d_in[6];
  const float* bih  = (const float*)d_in[7];
  const float* bhh  = (const float*)d_in[8];
  const float* Wout = (const float*)d_in[9];
  const float* bout = (const float*)d_in[10];
  float* out = (float*)d_out;

  unsigned short* Whhp3 = (unsigned short*)d_ws;                       // 393216 B
  unsigned short* Wh0p  = (unsigned short*)((char*)d_ws + 393216);     // 163840 B
  float* gpo = (float*)((char*)d_ws + 393216 + 163840);                // 12288 B

  hipLaunchKernelGGL(prep_whh3_k, dim3(768), dim3(256), 0, stream, Whh, Whhp3);
  hipLaunchKernelGGL(prep_wh0_k, dim3(320), dim3(256), 0, stream, Wh0, Wh0p);
  hipLaunchKernelGGL(prep_gp_k, dim3(1), dim3(256), 0, stream, bih, bhh, Wih, Wout, gpo);
  hipLaunchKernelGGL(gru_main_k, dim3(512), dim3(512), 0, stream,
                     ctx, goals, emb, bh0, bout, Wh0p, Whhp3, gpo, out);
  hipLaunchKernelGGL(corr_k, dim3(12288), dim3(256), 0, stream, out, goals);
}

// Round 4
// 1660.801 us; speedup vs baseline: 12.8029x; 12.8029x over previous
//
#include <hip/hip_runtime.h>

// TrajectoryDecoder r4: r1 structure + continuously-pipelined weight stream.
// MFMA 32x32x16 bf16. BK=49152, T=30, H=256. Block=96 seqs, 512 thr (8 waves),
// grid 512 (1 block/CU, 2 rounds). Weights streamed global->VGPR via a depth-4
// register ring (prefetch distance 3, addresses periodic mod 16 so the ring
// pipelines across step boundaries). Barriers are lgkm-only (LDS-protecting):
// weight loads stay in flight across barriers -- no vmcnt(0) drain anywhere in
// the t-loop. h carried bf16-packed in 24 regs; acc 144 AGPR; arch VGPR ~120.

typedef __attribute__((ext_vector_type(8))) short short8;
typedef __bf16 bf16x8 __attribute__((ext_vector_type(8)));
typedef float f32x16 __attribute__((ext_vector_type(16)));
typedef float f32x4 __attribute__((ext_vector_type(4)));

#define HSTR 264               // Hb stride (bf16): 528B rows; ~0 conflicts measured (r2/r3)
#define NSEQ_BLK 96
#define WHH3_ELEMS (24 * 16 * 64 * 8)  // 196608 = 768x256
#define WH0_ELEMS (8 * 20 * 64 * 8)    // 81920

static __device__ __forceinline__ unsigned short f2bf(float f) {
  unsigned u = __builtin_bit_cast(unsigned, f);
  u += 0x7fffu + ((u >> 16) & 1u);   // RNE
  return (unsigned short)(u >> 16);
}
static __device__ __forceinline__ float bf2f(unsigned short h) {
  unsigned u = ((unsigned)h) << 16;
  return __builtin_bit_cast(float, u);
}
static __device__ __forceinline__ bf16x8 ldfrag(const unsigned short* p) {
  return __builtin_bit_cast(bf16x8, *(const short8*)p);
}
static __device__ __forceinline__ float fsig(float x) {
  return __builtin_amdgcn_rcpf(1.f + __builtin_amdgcn_exp2f(-1.44269504f * x));
}
static __device__ __forceinline__ float ftanh(float x) {
  return 1.f - 2.f * __builtin_amdgcn_rcpf(1.f + __builtin_amdgcn_exp2f(2.88539008f * x));
}
static __device__ __forceinline__ float dpp16sum(float x) {
  x += __builtin_bit_cast(float, __builtin_amdgcn_update_dpp(0, __builtin_bit_cast(int, x), 0xB1, 0xF, 0xF, true));
  x += __builtin_bit_cast(float, __builtin_amdgcn_update_dpp(0, __builtin_bit_cast(int, x), 0x4E, 0xF, 0xF, true));
  x += __builtin_bit_cast(float, __builtin_amdgcn_update_dpp(0, __builtin_bit_cast(int, x), 0x141, 0xF, 0xF, true));
  x += __builtin_bit_cast(float, __builtin_amdgcn_update_dpp(0, __builtin_bit_cast(int, x), 0x140, 0xF, 0xF, true));
  return x;
}
// LDS-only barrier: does NOT drain vmcnt -- weight prefetches stay in flight.
// Safe because barriers here only order LDS (Hb/dpart/posL); vmem ops in the
// t-loop are register-private loads and the out[] store nobody reads.
static __device__ __forceinline__ void bar_lgkm() {
  asm volatile("s_waitcnt lgkmcnt(0)\n\ts_barrier" ::: "memory");
}

// ---- prep: pack W_hh slice-major: [(g*8+w)*16 + ks][lane][8] ----
// row(N) = g*256 + w*32 + (lane&31), k = ks*16 + (lane>>5)*8 + j
__global__ void prep_whh3_k(const float* __restrict__ Whh, unsigned short* __restrict__ Whhp3) {
  int i = blockIdx.x * 256 + threadIdx.x;
  if (i >= WHH3_ELEMS) return;
  int j = i & 7;
  int lane = (i >> 3) & 63;
  int rest = i >> 9;            // (g*8+w)*16 + ks
  int ks = rest & 15;
  int sw = rest >> 4;           // 0..23
  int g = sw >> 3, w = sw & 7;
  int row = g * 256 + w * 32 + (lane & 31);
  int k = ks * 16 + ((lane >> 5) << 3) + j;
  Whhp3[i] = f2bf(Whh[row * 256 + k]);
}

// ---- prep: pack W_h0 (256 x 290, K padded to 320): [nt][ks 0..19][lane][8] ----
__global__ void prep_wh0_k(const float* __restrict__ Wh0, unsigned short* __restrict__ Wh0p) {
  int i = blockIdx.x * 256 + threadIdx.x;
  if (i >= WH0_ELEMS) return;
  int j = i & 7;
  int lane = (i >> 3) & 63;
  int rest = i >> 9;            // nt*20 + ks
  int ks = rest % 20;
  int nt = rest / 20;
  int row = nt * 32 + (lane & 31);
  int k = ks * 16 + ((lane >> 5) << 3) + j;
  float v = (k < 290) ? Wh0[row * 290 + k] : 0.f;
  Wh0p[i] = f2bf(v);
}

// ---- prep: per-h-unit params [br,bz,bin,bhn, wr0,wr1, wz0,wz1, wn0,wn1, wo0,wo1] ----
__global__ void prep_gp_k(const float* __restrict__ bih, const float* __restrict__ bhh,
                          const float* __restrict__ Wih, const float* __restrict__ Wout,
                          float* __restrict__ gpo) {
  int n = threadIdx.x;   // 256
  gpo[n * 12 + 0]  = bih[n] + bhh[n];
  gpo[n * 12 + 1]  = bih[n + 256] + bhh[n + 256];
  gpo[n * 12 + 2]  = bih[n + 512];
  gpo[n * 12 + 3]  = bhh[n + 512];
  gpo[n * 12 + 4]  = Wih[n * 2 + 0];
  gpo[n * 12 + 5]  = Wih[n * 2 + 1];
  gpo[n * 12 + 6]  = Wih[(n + 256) * 2 + 0];
  gpo[n * 12 + 7]  = Wih[(n + 256) * 2 + 1];
  gpo[n * 12 + 8]  = Wih[(n + 512) * 2 + 0];
  gpo[n * 12 + 9]  = Wih[(n + 512) * 2 + 1];
  gpo[n * 12 + 10] = Wout[n];
  gpo[n * 12 + 11] = Wout[256 + n];
}

// ---------------- main fused GRU ----------------
__global__ __launch_bounds__(512, 2) void gru_main_k(
    const float* __restrict__ ctx, const float* __restrict__ goals,
    const float* __restrict__ emb, const float* __restrict__ bh0,
    const float* __restrict__ bout,
    const unsigned short* __restrict__ Wh0p,
    const unsigned short* __restrict__ Whhp3,
    const float* __restrict__ gp,
    float* __restrict__ out) {
  __shared__ __align__(16) unsigned short Hb[NSEQ_BLK * HSTR];   // 50688 B
  __shared__ __align__(16) float dpart[16 * NSEQ_BLK * 2];       // 12288 B
  __shared__ __align__(16) float posL[NSEQ_BLK * 2];             // 768 B

  const int tid = threadIdx.x;
  const int w = tid >> 6;
  const int l = tid & 63;
  const int l31 = l & 31;
  const int grp = l >> 5;
  const int seq0 = blockIdx.x * NSEQ_BLK;
  const int n0 = w * 32 + l31;

  // per-(wave,lane) weight base: gate stride 65536 elems, ks stride 512 elems
  const unsigned short* wg = Whhp3 + w * 8192 + l * 8;

  // ---------------- Phase 0: h0 = init_in @ W_h0^T + b_h0 ----------------
  f32x16 acc0[3];
  acc0[0] = f32x16{};
  acc0[1] = f32x16{};
  acc0[2] = f32x16{};
  unsigned short* As = Hb;   // overlay staging, stride 176
  for (int cc = 0; cc < 2; ++cc) {
    for (int i = tid; i < NSEQ_BLK * 160; i += 512) {
      int row = i / 160;
      int col = i - row * 160;
      int d = cc * 160 + col;
      int s = seq0 + row;
      int b = s / 6;
      float v;
      if (d < 256)      v = ctx[b * 256 + d];
      else if (d < 258) v = goals[s * 2 + (d - 256)];
      else if (d < 290) v = emb[b * 32 + (d - 258)];
      else              v = 0.f;
      As[row * 176 + col] = f2bf(v);
    }
    __syncthreads();
    for (int ks = 0; ks < 10; ++ks) {
      bf16x8 bf = ldfrag(&Wh0p[((w * 20 + cc * 10 + ks) * 64 + l) * 8]);
#pragma unroll
      for (int mc = 0; mc < 3; ++mc) {
        bf16x8 af = ldfrag(&As[(mc * 32 + l31) * 176 + ks * 16 + grp * 8]);
        acc0[mc] = __builtin_amdgcn_mfma_f32_32x32x16_bf16(af, bf, acc0[mc], 0, 0, 0);
      }
    }
    __syncthreads();
  }
  // epilogue: bf16 h packed in regs (24 VGPRs) + bf16 copy in Hb
  unsigned hpk[3][8];
  {
    float b0 = bh0[n0];
#pragma unroll
    for (int mc = 0; mc < 3; ++mc) {
      unsigned tmp = 0;
#pragma unroll
      for (int r = 0; r < 16; ++r) {
        int row = (r & 3) + 8 * (r >> 2) + 4 * grp;
        unsigned short hb = f2bf(acc0[mc][r] + b0);
        Hb[(mc * 32 + row) * HSTR + n0] = hb;
        if ((r & 1) == 0) tmp = hb;
        else hpk[mc][r >> 1] = tmp | ((unsigned)hb << 16);
      }
    }
  }
  if (tid < 192) posL[tid] = 0.f;

  float brr, bzz, bin_, bhn, wr0, wr1, wz0, wz1, wn0, wn1, wo0, wo1;
  {
    f32x4 g0 = *(const f32x4*)&gp[n0 * 12];
    f32x4 g1 = *(const f32x4*)&gp[n0 * 12 + 4];
    f32x4 g2 = *(const f32x4*)&gp[n0 * 12 + 8];
    brr = g0[0]; bzz = g0[1]; bin_ = g0[2]; bhn = g0[3];
    wr0 = g1[0]; wr1 = g1[1]; wz0 = g1[2]; wz1 = g1[3];
    wn0 = g2[0]; wn1 = g2[1]; wo0 = g2[2]; wo1 = g2[3];
  }
  const float bo0 = bout[0], bo1 = bout[1];
  __syncthreads();

  // ---- weight ring: depth 4, prefetch distance 3 (48 VGPRs) ----
  bf16x8 ring[4][3];
#pragma unroll
  for (int p = 0; p < 3; ++p) {
    ring[p][0] = ldfrag(wg + p * 512);
    ring[p][1] = ldfrag(wg + 65536 + p * 512);
    ring[p][2] = ldfrag(wg + 131072 + p * 512);
  }

  // ---------------- T recurrent steps ----------------
  for (int t = 0; t < 30; ++t) {
    f32x16 ar[3], az[3], an[3];
#pragma unroll
    for (int mc = 0; mc < 3; ++mc) { ar[mc] = f32x16{}; az[mc] = f32x16{}; an[mc] = f32x16{}; }

    // Phase A: K-loop. Prefetch (ks+3)&15 -> slot (ks+3)&3; consume slot ks&3.
    // Address pattern is t-invariant, so the ring never winds down across steps.
#pragma unroll
    for (int ks = 0; ks < 16; ++ks) {
      const int kp = ((ks + 3) & 15) * 512;
      const int sp = (ks + 3) & 3;
      ring[sp][0] = ldfrag(wg + kp);
      ring[sp][1] = ldfrag(wg + 65536 + kp);
      ring[sp][2] = ldfrag(wg + 131072 + kp);
      const int sl = ks & 3;
      const unsigned short* ab = &Hb[l31 * HSTR + ks * 16 + grp * 8];
#pragma unroll
      for (int mc = 0; mc < 3; ++mc) {
        bf16x8 af = ldfrag(ab + mc * 32 * HSTR);
        ar[mc] = __builtin_amdgcn_mfma_f32_32x32x16_bf16(af, ring[sl][0], ar[mc], 0, 0, 0);
        az[mc] = __builtin_amdgcn_mfma_f32_32x32x16_bf16(af, ring[sl][1], az[mc], 0, 0, 0);
        an[mc] = __builtin_amdgcn_mfma_f32_32x32x16_bf16(af, ring[sl][2], an[mc], 0, 0, 0);
      }
    }
    bar_lgkm();   // barrier1: all Hb reads done; posL(t-1) final (lgkm-only!)

    // Phase B: gates + h update + delta partials (DPP 16-lane sums)
#pragma unroll
    for (int mc = 0; mc < 3; ++mc) {
#pragma unroll
      for (int q2 = 0; q2 < 4; ++q2) {
        int sb = mc * 32 + 8 * q2 + 4 * grp;
        f32x4 xyA = *(const f32x4*)&posL[sb * 2];
        f32x4 xyB = *(const f32x4*)&posL[sb * 2 + 4];
#pragma unroll
        for (int e = 0; e < 4; ++e) {
          int r = 4 * q2 + e;
          int s = sb + e;
          float x = (e == 0) ? xyA[0] : (e == 1) ? xyA[2] : (e == 2) ? xyB[0] : xyB[2];
          float y = (e == 0) ? xyA[1] : (e == 1) ? xyA[3] : (e == 2) ? xyB[1] : xyB[3];
          unsigned hp = hpk[mc][r >> 1];
          float h = bf2f((unsigned short)((r & 1) ? (hp >> 16) : (hp & 0xffffu)));
          float rg = fsig(ar[mc][r] + brr + x * wr0 + y * wr1);
          float zg = fsig(az[mc][r] + bzz + x * wz0 + y * wz1);
          float ng = ftanh(fmaf(rg, an[mc][r] + bhn, fmaf(x, wn0, fmaf(y, wn1, bin_))));
          float hnew = fmaf(zg, h - ng, ng);     // (1-z)*n + z*h
          unsigned short nb = f2bf(hnew);
          hpk[mc][r >> 1] = (r & 1) ? ((hp & 0xffffu) | ((unsigned)nb << 16))
                                    : ((hp & 0xffff0000u) | nb);
          Hb[s * HSTR + n0] = nb;
          float dx = dpp16sum(hnew * wo0);
          float dy = dpp16sum(hnew * wo1);
          if ((l & 15) == 0) {
            int p16 = w * 2 + ((l >> 4) & 1);
            dpart[(p16 * NSEQ_BLK + s) * 2]     = dx;
            dpart[(p16 * NSEQ_BLK + s) * 2 + 1] = dy;
          }
        }
      }
    }
    bar_lgkm();   // barrier2: Hb h-writes + dpart visible (lgkm-only)

    // Phase C (threads 0-191): pos update + raw pred store; overlaps next K-loop
    if (tid < 192) {
      int s = tid >> 1, c = tid & 1;
      float d = (c == 0) ? bo0 : bo1;
#pragma unroll
      for (int q = 0; q < 16; ++q) d += dpart[(q * NSEQ_BLK + s) * 2 + c];
      float p = posL[tid] + d;
      posL[tid] = p;
      out[((seq0 + s) * 30 + t) * 2 + c] = p;
    }
  }
}

// ---- correction: out = pred + (goal - pred_T) * (t+1)/30, in place ----
__global__ void corr_k(float* __restrict__ out, const float* __restrict__ goals) {
  __shared__ float buf[240];
  int tid = threadIdx.x;
  int s0 = blockIdx.x * 4;
  float v = 0.f;
  if (tid < 240) { v = out[s0 * 60 + tid]; buf[tid] = v; }
  __syncthreads();
  if (tid < 240) {
    int sl = tid / 60;
    int rem = tid - sl * 60;
    int t = rem >> 1, c = rem & 1;
    float pT = buf[sl * 60 + 58 + c];
    float g = goals[(s0 + sl) * 2 + c];
    out[s0 * 60 + tid] = v + (g - pT) * ((float)(t + 1) * (1.f / 30.f));
  }
}

extern "C" void kernel_launch(void* const* d_in, const int* in_sizes, int n_in,
                              void* d_out, int out_size, void* d_ws, size_t ws_size,
                              hipStream_t stream) {
  (void)in_sizes; (void)n_in; (void)out_size; (void)ws_size;
  const float* ctx  = (const float*)d_in[0];
  const float* goals= (const float*)d_in[1];
  const float* emb  = (const float*)d_in[2];
  const float* Wh0  = (const float*)d_in[3];
  const float* bh0  = (const float*)d_in[4];
  const float* Wih  = (const float*)d_in[5];
  const float* Whh  = (const float*)d_in[6];
  const float* bih  = (const float*)d_in[7];
  const float* bhh  = (const float*)d_in[8];
  const float* Wout = (const float*)d_in[9];
  const float* bout = (const float*)d_in[10];
  float* out = (float*)d_out;

  unsigned short* Whhp3 = (unsigned short*)d_ws;                       // 393216 B
  unsigned short* Wh0p  = (unsigned short*)((char*)d_ws + 393216);     // 163840 B
  float* gpo = (float*)((char*)d_ws + 393216 + 163840);                // 12288 B

  hipLaunchKernelGGL(prep_whh3_k, dim3(768), dim3(256), 0, stream, Whh, Whhp3);
  hipLaunchKernelGGL(prep_wh0_k, dim3(320), dim3(256), 0, stream, Wh0, Wh0p);
  hipLaunchKernelGGL(prep_gp_k, dim3(1), dim3(256), 0, stream, bih, bhh, Wih, Wout, gpo);
  hipLaunchKernelGGL(gru_main_k, dim3(512), dim3(512), 0, stream,
                     ctx, goals, emb, bh0, bout, Wh0p, Whhp3, gpo, out);
  hipLaunchKernelGGL(corr_k, dim3(12288), dim3(256), 0, stream, out, goals);
}

// Round 6
// 989.885 us; speedup vs baseline: 21.4803x; 1.6778x over previous
//
#include <hip/hip_runtime.h>

// TrajectoryDecoder r6: spill-free register/LDS-stationary GRU.
// MFMA 32x32x16 bf16. BK=49152, T=30, H=256. Block = 32 seqs, 512 thr
// (8 waves), grid 1536 (1 block/CU, 6 rounds). Register budget CLOSES:
// wR,wZ register-stationary (128 regs) + acc 48 + temps ~35 = ~215 <= 256
// cap at 2 waves/SIMD. wN lives in LDS (128 KB, block-shared, staged once).
// Zero global traffic in the t-loop. All logic taken from rounds that PASSED:
// r3 preload/prep/phaseB/C + DPP delta, r2 h-from-Hb, r4 lgkm-only barriers.

typedef __attribute__((ext_vector_type(8))) short short8;
typedef __bf16 bf16x8 __attribute__((ext_vector_type(8)));
typedef float f32x16 __attribute__((ext_vector_type(16)));
typedef float f32x4 __attribute__((ext_vector_type(4)));

#define HSTR 264               // Hb stride (bf16): 528B rows; ~0 conflicts measured
#define NSEQ_BLK 32
#define WHH3_ELEMS (24 * 16 * 64 * 8)  // 196608 = 768x256
#define WH0_ELEMS (8 * 20 * 64 * 8)    // 81920

static __device__ __forceinline__ unsigned short f2bf(float f) {
  unsigned u = __builtin_bit_cast(unsigned, f);
  u += 0x7fffu + ((u >> 16) & 1u);   // RNE
  return (unsigned short)(u >> 16);
}
static __device__ __forceinline__ float bf2f(unsigned short h) {
  unsigned u = ((unsigned)h) << 16;
  return __builtin_bit_cast(float, u);
}
static __device__ __forceinline__ bf16x8 ldfrag(const unsigned short* p) {
  return __builtin_bit_cast(bf16x8, *(const short8*)p);
}
static __device__ __forceinline__ float fsig(float x) {
  return __builtin_amdgcn_rcpf(1.f + __builtin_amdgcn_exp2f(-1.44269504f * x));
}
static __device__ __forceinline__ float ftanh(float x) {
  return 1.f - 2.f * __builtin_amdgcn_rcpf(1.f + __builtin_amdgcn_exp2f(2.88539008f * x));
}
static __device__ __forceinline__ float dpp16sum(float x) {
  x += __builtin_bit_cast(float, __builtin_amdgcn_update_dpp(0, __builtin_bit_cast(int, x), 0xB1, 0xF, 0xF, true));
  x += __builtin_bit_cast(float, __builtin_amdgcn_update_dpp(0, __builtin_bit_cast(int, x), 0x4E, 0xF, 0xF, true));
  x += __builtin_bit_cast(float, __builtin_amdgcn_update_dpp(0, __builtin_bit_cast(int, x), 0x141, 0xF, 0xF, true));
  x += __builtin_bit_cast(float, __builtin_amdgcn_update_dpp(0, __builtin_bit_cast(int, x), 0x140, 0xF, 0xF, true));
  return x;
}
// LDS-only barrier (r4-verified): no vmcnt drain; t-loop vmem = out stores only.
static __device__ __forceinline__ void bar_lgkm() {
  asm volatile("s_waitcnt lgkmcnt(0)\n\ts_barrier" ::: "memory");
}

// ---- prep: pack W_hh slice-major: [(g*8+w)*16 + ks][lane][8]  (r3-verified) ----
__global__ void prep_whh3_k(const float* __restrict__ Whh, unsigned short* __restrict__ Whhp3) {
  int i = blockIdx.x * 256 + threadIdx.x;
  if (i >= WHH3_ELEMS) return;
  int j = i & 7;
  int lane = (i >> 3) & 63;
  int rest = i >> 9;
  int ks = rest & 15;
  int sw = rest >> 4;
  int g = sw >> 3, w = sw & 7;
  int row = g * 256 + w * 32 + (lane & 31);
  int k = ks * 16 + ((lane >> 5) << 3) + j;
  Whhp3[i] = f2bf(Whh[row * 256 + k]);
}

// ---- prep: pack W_h0 (256 x 290, K padded to 320)  (r3-verified) ----
__global__ void prep_wh0_k(const float* __restrict__ Wh0, unsigned short* __restrict__ Wh0p) {
  int i = blockIdx.x * 256 + threadIdx.x;
  if (i >= WH0_ELEMS) return;
  int j = i & 7;
  int lane = (i >> 3) & 63;
  int rest = i >> 9;
  int ks = rest % 20;
  int nt = rest / 20;
  int row = nt * 32 + (lane & 31);
  int k = ks * 16 + ((lane >> 5) << 3) + j;
  float v = (k < 290) ? Wh0[row * 290 + k] : 0.f;
  Wh0p[i] = f2bf(v);
}

// ---- prep: per-h-unit params (r3-verified) ----
__global__ void prep_gp_k(const float* __restrict__ bih, const float* __restrict__ bhh,
                          const float* __restrict__ Wih, const float* __restrict__ Wout,
                          float* __restrict__ gpo) {
  int n = threadIdx.x;
  gpo[n * 12 + 0]  = bih[n] + bhh[n];
  gpo[n * 12 + 1]  = bih[n + 256] + bhh[n + 256];
  gpo[n * 12 + 2]  = bih[n + 512];
  gpo[n * 12 + 3]  = bhh[n + 512];
  gpo[n * 12 + 4]  = Wih[n * 2 + 0];
  gpo[n * 12 + 5]  = Wih[n * 2 + 1];
  gpo[n * 12 + 6]  = Wih[(n + 256) * 2 + 0];
  gpo[n * 12 + 7]  = Wih[(n + 256) * 2 + 1];
  gpo[n * 12 + 8]  = Wih[(n + 512) * 2 + 0];
  gpo[n * 12 + 9]  = Wih[(n + 512) * 2 + 1];
  gpo[n * 12 + 10] = Wout[n];
  gpo[n * 12 + 11] = Wout[256 + n];
}

// ---------------- main fused GRU ----------------
__global__ __launch_bounds__(512, 2) void gru_main_k(
    const float* __restrict__ ctx, const float* __restrict__ goals,
    const float* __restrict__ emb, const float* __restrict__ bh0,
    const float* __restrict__ bout,
    const unsigned short* __restrict__ Wh0p,
    const unsigned short* __restrict__ Whhp3,
    const float* __restrict__ gp,
    float* __restrict__ out) {
  __shared__ __align__(16) unsigned short wNl[8 * 16 * 64 * 8];  // 131072 B (n-gate weights)
  __shared__ __align__(16) unsigned short Hb[NSEQ_BLK * HSTR];   // 16896 B
  __shared__ __align__(16) float dpart[16 * NSEQ_BLK * 2];       // 4096 B
  __shared__ __align__(16) float posL[NSEQ_BLK * 2];             // 256 B
  // total 152320 B <= 160 KiB; 1 block/CU, 8 waves (2/SIMD)

  const int tid = threadIdx.x;
  const int w = tid >> 6;
  const int l = tid & 63;
  const int l31 = l & 31;
  const int grp = l >> 5;
  const int seq0 = blockIdx.x * NSEQ_BLK;
  const int n0 = w * 32 + l31;

  // ---- stage wN (g=2 region of Whhp3, 128 KB) into LDS, block-cooperative ----
  {
    const short8* wsrc = (const short8*)(Whhp3 + 131072);
    short8* wdst = (short8*)wNl;
    for (int i = tid; i < 8192; i += 512) wdst[i] = wsrc[i];
  }
  // ---- preload wR, wZ into registers (held for all 30 steps; 128 regs) ----
  bf16x8 wR[16], wZ[16];
#pragma unroll
  for (int ks = 0; ks < 16; ++ks) {
    wR[ks] = ldfrag(&Whhp3[(((0 * 8 + w) * 16 + ks) * 64 + l) * 8]);
    wZ[ks] = ldfrag(&Whhp3[(((1 * 8 + w) * 16 + ks) * 64 + l) * 8]);
  }

  // ---------------- Phase 0: h0 = init_in @ W_h0^T + b_h0 ----------------
  f32x16 acc0 = f32x16{};
  unsigned short* As = Hb;   // overlay staging, stride 176 (5632 shorts < 8448)
  for (int cc = 0; cc < 2; ++cc) {
    for (int i = tid; i < NSEQ_BLK * 160; i += 512) {
      int row = i / 160;
      int col = i - row * 160;
      int d = cc * 160 + col;
      int s = seq0 + row;
      int b = s / 6;
      float v;
      if (d < 256)      v = ctx[b * 256 + d];
      else if (d < 258) v = goals[s * 2 + (d - 256)];
      else if (d < 290) v = emb[b * 32 + (d - 258)];
      else              v = 0.f;
      As[row * 176 + col] = f2bf(v);
    }
    __syncthreads();   // also orders the wNl staging writes (cc=0)
    for (int ks = 0; ks < 10; ++ks) {
      bf16x8 bf = ldfrag(&Wh0p[((w * 20 + cc * 10 + ks) * 64 + l) * 8]);
      bf16x8 af = ldfrag(&As[l31 * 176 + ks * 16 + grp * 8]);
      acc0 = __builtin_amdgcn_mfma_f32_32x32x16_bf16(af, bf, acc0, 0, 0, 0);
    }
    __syncthreads();
  }
  {
    float b0 = bh0[n0];
#pragma unroll
    for (int r = 0; r < 16; ++r) {
      int row = (r & 3) + 8 * (r >> 2) + 4 * grp;   // C/D layout [m74/m101]
      Hb[row * HSTR + n0] = f2bf(acc0[r] + b0);
    }
  }
  if (tid < 2 * NSEQ_BLK) posL[tid] = 0.f;

  float brr, bzz, bin_, bhn, wr0, wr1, wz0, wz1, wn0, wn1, wo0, wo1;
  {
    f32x4 g0 = *(const f32x4*)&gp[n0 * 12];
    f32x4 g1 = *(const f32x4*)&gp[n0 * 12 + 4];
    f32x4 g2 = *(const f32x4*)&gp[n0 * 12 + 8];
    brr = g0[0]; bzz = g0[1]; bin_ = g0[2]; bhn = g0[3];
    wr0 = g1[0]; wr1 = g1[1]; wz0 = g1[2]; wz1 = g1[3];
    wn0 = g2[0]; wn1 = g2[1]; wo0 = g2[2]; wo1 = g2[3];
  }
  const float bo0 = bout[0], bo1 = bout[1];
  __syncthreads();

  // ---------------- T recurrent steps (no global loads inside) ----------------
  for (int t = 0; t < 30; ++t) {
    f32x16 ar = f32x16{}, az = f32x16{}, an = f32x16{};

    // K-loop: A from Hb (LDS), wR/wZ from regs, wN from LDS
#pragma unroll
    for (int ks = 0; ks < 16; ++ks) {
      bf16x8 af = ldfrag(&Hb[l31 * HSTR + ks * 16 + grp * 8]);
      bf16x8 bN = ldfrag(&wNl[((w * 16 + ks) * 64 + l) * 8]);
      ar = __builtin_amdgcn_mfma_f32_32x32x16_bf16(af, wR[ks], ar, 0, 0, 0);
      az = __builtin_amdgcn_mfma_f32_32x32x16_bf16(af, wZ[ks], az, 0, 0, 0);
      an = __builtin_amdgcn_mfma_f32_32x32x16_bf16(af, bN, an, 0, 0, 0);
    }
    bar_lgkm();   // barrier1: Hb reads done; posL(t-1) final

    // Phase B: gates + h update + delta partials (r3-verified structure)
#pragma unroll
    for (int q2 = 0; q2 < 4; ++q2) {
      int sb = 8 * q2 + 4 * grp;
      f32x4 xyA = *(const f32x4*)&posL[sb * 2];
      f32x4 xyB = *(const f32x4*)&posL[sb * 2 + 4];
#pragma unroll
      for (int e = 0; e < 4; ++e) {
        int r = 4 * q2 + e;
        int s = sb + e;
        float x = (e == 0) ? xyA[0] : (e == 1) ? xyA[2] : (e == 2) ? xyB[0] : xyB[2];
        float y = (e == 0) ? xyA[1] : (e == 1) ? xyA[3] : (e == 2) ? xyB[1] : xyB[3];
        int ha = s * HSTR + n0;
        float h = bf2f(Hb[ha]);
        float rg = fsig(ar[r] + brr + x * wr0 + y * wr1);
        float zg = fsig(az[r] + bzz + x * wz0 + y * wz1);
        float ng = ftanh(fmaf(rg, an[r] + bhn, fmaf(x, wn0, fmaf(y, wn1, bin_))));
        float hnew = fmaf(zg, h - ng, ng);     // (1-z)*n + z*h
        Hb[ha] = f2bf(hnew);
        float dx = dpp16sum(hnew * wo0);
        float dy = dpp16sum(hnew * wo1);
        if ((l & 15) == 0) {
          int p16 = w * 2 + ((l >> 4) & 1);
          dpart[(p16 * NSEQ_BLK + s) * 2]     = dx;
          dpart[(p16 * NSEQ_BLK + s) * 2 + 1] = dy;
        }
      }
    }
    bar_lgkm();   // barrier2: Hb h-writes + dpart visible

    // Phase C (wave 0): pos update + raw pred store
    if (tid < 2 * NSEQ_BLK) {
      int s = tid >> 1, c = tid & 1;
      float d = (c == 0) ? bo0 : bo1;
#pragma unroll
      for (int q = 0; q < 16; ++q) d += dpart[(q * NSEQ_BLK + s) * 2 + c];
      float p = posL[tid] + d;
      posL[tid] = p;
      out[((seq0 + s) * 30 + t) * 2 + c] = p;
    }
  }
}

// ---- correction: out = pred + (goal - pred_T) * (t+1)/30, in place (verified) ----
__global__ void corr_k(float* __restrict__ out, const float* __restrict__ goals) {
  __shared__ float buf[240];
  int tid = threadIdx.x;
  int s0 = blockIdx.x * 4;
  float v = 0.f;
  if (tid < 240) { v = out[s0 * 60 + tid]; buf[tid] = v; }
  __syncthreads();
  if (tid < 240) {
    int sl = tid / 60;
    int rem = tid - sl * 60;
    int t = rem >> 1, c = rem & 1;
    float pT = buf[sl * 60 + 58 + c];
    float g = goals[(s0 + sl) * 2 + c];
    out[s0 * 60 + tid] = v + (g - pT) * ((float)(t + 1) * (1.f / 30.f));
  }
}

extern "C" void kernel_launch(void* const* d_in, const int* in_sizes, int n_in,
                              void* d_out, int out_size, void* d_ws, size_t ws_size,
                              hipStream_t stream) {
  (void)in_sizes; (void)n_in; (void)out_size; (void)ws_size;
  const float* ctx  = (const float*)d_in[0];
  const float* goals= (const float*)d_in[1];
  const float* emb  = (const float*)d_in[2];
  const float* Wh0  = (const float*)d_in[3];
  const float* bh0  = (const float*)d_in[4];
  const float* Wih  = (const float*)d_in[5];
  const float* Whh  = (const float*)d_in[6];
  const float* bih  = (const float*)d_in[7];
  const float* bhh  = (const float*)d_in[8];
  const float* Wout = (const float*)d_in[9];
  const float* bout = (const float*)d_in[10];
  float* out = (float*)d_out;

  unsigned short* Whhp3 = (unsigned short*)d_ws;                       // 393216 B
  unsigned short* Wh0p  = (unsigned short*)((char*)d_ws + 393216);     // 163840 B
  float* gpo = (float*)((char*)d_ws + 393216 + 163840);                // 12288 B

  hipLaunchKernelGGL(prep_whh3_k, dim3(768), dim3(256), 0, stream, Whh, Whhp3);
  hipLaunchKernelGGL(prep_wh0_k, dim3(320), dim3(256), 0, stream, Wh0, Wh0p);
  hipLaunchKernelGGL(prep_gp_k, dim3(1), dim3(256), 0, stream, bih, bhh, Wih, Wout, gpo);
  hipLaunchKernelGGL(gru_main_k, dim3(1536), dim3(512), 0, stream,
                     ctx, goals, emb, bh0, bout, Wh0p, Whhp3, gpo, out);
  hipLaunchKernelGGL(corr_k, dim3(12288), dim3(256), 0, stream, out, goals);
}